// Round 15
// baseline (896.888 us; speedup 1.0000x reference)
//
#include <hip/hip_runtime.h>
#include <type_traits>

// LSTMNet: B=1024, T=2048, H=64, NC=10, input_size=1.
// MFMA (16x16x32 bf16) single-pass (W,h bf16 — R14-verified, absmax 9.8e-4).
// R15: UNIT-SPLIT waves -> in-register update, ONE barrier/step.
//   R14 was chain-latency-bound (999 cyc/step): two LDS round-trips + two
//   barriers (gate-split waves forced a gbuf exchange). Fix: wave w owns
//   units [16w,16w+16) x ALL 4 gates (tiles w*4+g; still 8 MFMAs/wave).
//   C-layout puts rows 0-1 in quad-0 lanes -> i,f,g,o for cell (r,u) sit in
//   one lane's accs -> update in-register (cc0,cc1 regs), h written straight
//   to the swizzled A-buffer, single barrier. gbuf deleted.
// Structure (R12-14-verified): 512 blocks x 256 thr (4 waves), 2 rows/block,
// 2 blocks/CU via 32KB-staging LDS union; swizzled abuf (2-way banks);
// x staged in 128-step chunks; t-loop unrolled x2 (compile-time ping-pong).

#define T_STEPS 2048
#define HID 64
#define NCLS 10
#define XCH 128   // x chunk length (steps)
#define ROWS 2    // batch rows per block

typedef short bf16x8 __attribute__((ext_vector_type(8)));
typedef float f32x4 __attribute__((ext_vector_type(4)));

__device__ __forceinline__ float sigm(float x) {
    float e = __builtin_amdgcn_exp2f(-1.4426950408889634f * x);
    return __builtin_amdgcn_rcpf(1.0f + e);
}
__device__ __forceinline__ float tanh_f(float x) {
    float e = __builtin_amdgcn_exp2f(-2.8853900817779268f * x);
    return fmaf(2.0f, __builtin_amdgcn_rcpf(1.0f + e), -1.0f);
}
__device__ __forceinline__ unsigned short f2bf(float f) {  // RNE f32->bf16
    unsigned u = __builtin_bit_cast(unsigned, f);
    u = u + 0x7FFFu + ((u >> 16) & 1u);
    return (unsigned short)(u >> 16);
}

__global__ __attribute__((amdgpu_flat_work_group_size(256, 256),
                          amdgpu_waves_per_eu(2, 2)))
void lstm_mfma_kernel(
    const float* __restrict__ x,      // [B, 1, T]
    const float* __restrict__ W_ih,   // [256, 1]
    const float* __restrict__ W_hh,   // [256, 64]
    const float* __restrict__ b_ih,   // [256]
    const float* __restrict__ b_hh,   // [256]
    const float* __restrict__ fc1_w,  // [64, 64]
    const float* __restrict__ fc1_b,  // [64]
    const float* __restrict__ fc2_w,  // [10, 64]
    const float* __restrict__ fc2_b,  // [10]
    float* __restrict__ out)          // [B, 10]
{
    const int tid  = threadIdx.x;
    const int lane = tid & 63;
    const int w    = tid >> 6;        // wave id = unit-16-block
    const int quad = lane >> 4;
    const int col  = lane & 15;
    const int row0 = blockIdx.x * ROWS;

    // ---- LDS union: 32KB staging (dead after B-frag load) overlaps runtime ----
    __shared__ __align__(16) char smem[32768];
    short* whi = (short*)smem;                 // staging [0,32768)
    // runtime (valid only after the staging->register handoff sync):
    short (*abuf)[1088]        = (short(*)[1088])smem;              // 4352 B
    float (*xlds)[XCH + 4]     = (float(*)[XCH + 4])(smem + 4352);  // 1056 B
    float (*hf)[HID + 1]       = (float(*)[HID + 1])(smem + 5408);  //  520 B
    float (*r1buf)[HID + 1]    = (float(*)[HID + 1])(smem + 5928);  //  520 B

    // ---- stage: W_hh f32 -> bf16 fragments (R5-verified layout) ----
    for (int idx = tid; idx < 256 * 64; idx += 256) {
        int r_ = idx >> 6;            // gate-major row 0..255
        int k  = idx & 63;
        float f = W_hh[r_ * 64 + k];
        int g = r_ >> 6, u = r_ & 63;
        int u4 = u >> 4, n = u & 15;
        int kt = k >> 5, kq = (k & 31) >> 3, j = k & 7;
        int off = (((u4 * 4 + g) * 2 + kt) * 64 + (kq * 16 + n)) * 8 + j;
        whi[off] = (short)f2bf(f);
    }
    __syncthreads();

    // ---- B fragments -> registers: wave w = unit block, all 4 gates ----
    bf16x8 Bq[4][2];
    f32x4 biasC[4];
    const int u_l = w * 16 + col;     // this lane's unit (for C/D and update)
    #pragma unroll
    for (int g = 0; g < 4; ++g) {
        int t_ = w * 4 + g;
        #pragma unroll
        for (int kt = 0; kt < 2; ++kt) {
            int off = ((t_ * 2 + kt) * 64 + lane) * 8;
            Bq[g][kt] = *(const bf16x8*)&whi[off];
            asm volatile("" : "+v"(Bq[g][kt]));
        }
        float bs = b_ih[g * HID + u_l] + b_hh[g * HID + u_l];
        #pragma unroll
        for (int r = 0; r < 4; ++r) biasC[g][r] = bs;
    }
    __syncthreads();   // all waves done READING staging; smem may be reused now

    // zero BOTH A buffers (rows 2..15 never written -> stay zero = h0)
    for (int idx = tid; idx < 2 * 1088; idx += 256) ((short*)abuf)[idx] = 0;

    // ---- update constants: quad-0 lane handles cells (r=0,1 ; unit u_l) ----
    float wih_u[4];
    #pragma unroll
    for (int g = 0; g < 4; ++g) wih_u[g] = W_ih[g * HID + u_l];
    float cc0 = 0.f, cc1 = 0.f, hl0 = 0.f, hl1 = 0.f;

    // invariant LDS coords
    const int ard0 = lane * 8 + (lane >> 4) * 8;   // A-read (kt=1 at +544)
    // h-write swizzled slot for (m=r, k=u_l):
    //   s = (u>>5)*4 + ((u>>3)&3); off = (s*16+r)*8 + s*8 + (u&7); r=1 at +8
    const int s_w  = (u_l >> 5) * 4 + ((u_l >> 3) & 3);
    const int awr0 = (s_w * 16) * 8 + s_w * 8 + (u_l & 7);

    const float* xbase = x + (size_t)row0 * T_STEPS;
    __syncthreads();   // abuf zeroed

    auto step = [&](auto cur_c, int tl) __attribute__((always_inline)) {
        constexpr int CUR = decltype(cur_c)::value;
        constexpr int NXT = CUR ^ 1;

        // ---- compute: all 4 gates for units [16w,16w+16), 8 MFMAs ----
        bf16x8 Ahi0 = *(const bf16x8*)&abuf[CUR][ard0];
        bf16x8 Ahi1 = *(const bf16x8*)&abuf[CUR][ard0 + 544];

        f32x4 acc[4];
        #pragma unroll
        for (int g = 0; g < 4; ++g) {
            acc[g] = __builtin_amdgcn_mfma_f32_16x16x32_bf16(Ahi0, Bq[g][0], biasC[g], 0, 0, 0);
        }
        #pragma unroll
        for (int g = 0; g < 4; ++g) {
            acc[g] = __builtin_amdgcn_mfma_f32_16x16x32_bf16(Ahi1, Bq[g][1], acc[g], 0, 0, 0);
        }

        // ---- in-register update: quad-0 lanes own cells (r, u_l), r=0,1 ----
        if (quad == 0) {
            float xv0 = xlds[0][tl];   // wave-uniform broadcasts
            float xv1 = xlds[1][tl];

            float a00 = fmaf(xv0, wih_u[0], acc[0][0]);
            float a01 = fmaf(xv0, wih_u[1], acc[1][0]);
            float a02 = fmaf(xv0, wih_u[2], acc[2][0]);
            float a03 = fmaf(xv0, wih_u[3], acc[3][0]);
            float a10 = fmaf(xv1, wih_u[0], acc[0][1]);
            float a11 = fmaf(xv1, wih_u[1], acc[1][1]);
            float a12 = fmaf(xv1, wih_u[2], acc[2][1]);
            float a13 = fmaf(xv1, wih_u[3], acc[3][1]);

            float ig0 = sigm(a00), fg0 = sigm(a01), gg0 = tanh_f(a02), og0 = sigm(a03);
            float ig1 = sigm(a10), fg1 = sigm(a11), gg1 = tanh_f(a12), og1 = sigm(a13);
            cc0 = fmaf(fg0, cc0, ig0 * gg0);
            cc1 = fmaf(fg1, cc1, ig1 * gg1);
            float h0 = og0 * tanh_f(cc0);
            float h1 = og1 * tanh_f(cc1);
            hl0 = h0; hl1 = h1;

            abuf[NXT][awr0]     = (short)f2bf(h0);   // (m=0, k=u_l)
            abuf[NXT][awr0 + 8] = (short)f2bf(h1);   // (m=1, k=u_l)
        }
        __syncthreads();   // new h-frags visible to all waves
    };

    #pragma unroll 1
    for (int tc = 0; tc < T_STEPS; tc += 2) {
        const int tl = tc & (XCH - 1);
        if (tl == 0) {
            // refill x chunk (prev step barrier => old chunk fully consumed)
            if (tid < 16 * ROWS) {
                int xr = tid >> 4, tb = (tid & 15) * 8;
                const float* src = xbase + (size_t)xr * T_STEPS + tc + tb;
                float4 v0 = *(const float4*)(src);
                float4 v1 = *(const float4*)(src + 4);
                *(float4*)&xlds[xr][tb]     = v0;
                *(float4*)&xlds[xr][tb + 4] = v1;
            }
            __syncthreads();
        }
        step(std::integral_constant<int, 0>{}, tl);      // reads abuf[0], writes abuf[1]
        step(std::integral_constant<int, 1>{}, tl + 1);  // reads abuf[1], writes abuf[0]
    }

    // ---- epilogue: fc1 (relu) + fc2 ----
    if (quad == 0) {
        hf[0][u_l] = hl0;
        hf[1][u_l] = hl1;
    }
    __syncthreads();

    if (w < ROWS) {
        // thread -> (row = w, unit = lane)
        float s = fc1_b[lane];
        const float4* wrow = (const float4*)(fc1_w + lane * HID);
        #pragma unroll
        for (int j4 = 0; j4 < HID / 4; ++j4) {
            float4 wv = wrow[j4];
            s = fmaf(hf[w][j4 * 4 + 0], wv.x, s);
            s = fmaf(hf[w][j4 * 4 + 1], wv.y, s);
            s = fmaf(hf[w][j4 * 4 + 2], wv.z, s);
            s = fmaf(hf[w][j4 * 4 + 3], wv.w, s);
        }
        r1buf[w][lane] = fmaxf(s, 0.0f);
    }
    __syncthreads();

    if (tid < ROWS * NCLS) {
        int m = tid / NCLS, cls = tid % NCLS;
        float s = fc2_b[cls];
        const float* w2 = fc2_w + cls * HID;
        #pragma unroll
        for (int j = 0; j < HID; ++j) s = fmaf(r1buf[m][j], w2[j], s);
        out[(size_t)(row0 + m) * NCLS + cls] = s;
    }
}

extern "C" void kernel_launch(void* const* d_in, const int* in_sizes, int n_in,
                              void* d_out, int out_size, void* d_ws, size_t ws_size,
                              hipStream_t stream) {
    const float* x     = (const float*)d_in[0];
    const float* W_ih  = (const float*)d_in[1];
    const float* W_hh  = (const float*)d_in[2];
    const float* b_ih  = (const float*)d_in[3];
    const float* b_hh  = (const float*)d_in[4];
    const float* fc1_w = (const float*)d_in[5];
    const float* fc1_b = (const float*)d_in[6];
    const float* fc2_w = (const float*)d_in[7];
    const float* fc2_b = (const float*)d_in[8];
    float* out = (float*)d_out;

    dim3 grid(512);   // 1024 rows / 2 rows per block -> 2 blocks per CU
    dim3 block(256);  // 4 waves
    lstm_mfma_kernel<<<grid, block, 0, stream>>>(x, W_ih, W_hh, b_ih, b_hh,
                                                 fc1_w, fc1_b, fc2_w, fc2_b, out);
}

// Round 16
// 862.237 us; speedup vs baseline: 1.0402x; 1.0402x over previous
//
#include <hip/hip_runtime.h>
#include <type_traits>

// LSTMNet: B=1024, T=2048, H=64, NC=10, input_size=1.
// MFMA (16x16x32 bf16) single-pass (W,h bf16 — R14-verified, absmax 9.8e-4).
// R16: R11's 256-block shape + every verified fix since.
//   grid = 256 blocks x 256 thr (4 waves); block owns 4 rows; 1 block/CU.
//   vs R14 (512x2): HALVES per-CU MFMA (32x4.85=155cyc) and misc VALU.
//   vs R15: update is fully lane-packed (wave w = row w, lane = unit,
//   1 cell/thread, 4 waves balanced across SIMDs) — R15's exec-masked
//   trans (70% VALUBusy) was the regression.
//   gbuf[m][g][u] gate-planes (R14-verified: stride-1 b32 reads, free);
//   swizzled abuf (R10-verified); single-pass MFMA (R14-verified precision:
//   h-quantization noise dominates, absmax 9.8e-4); 32KB LDS union;
//   x chunked; t-loop unrolled x2. Two barriers/step (gbuf + abuf exchanges).

#define T_STEPS 2048
#define HID 64
#define NCLS 10
#define XCH 128   // x chunk length (steps)
#define ROWS 4    // batch rows per block

typedef short bf16x8 __attribute__((ext_vector_type(8)));
typedef float f32x4 __attribute__((ext_vector_type(4)));

__device__ __forceinline__ float sigm(float x) {
    float e = __builtin_amdgcn_exp2f(-1.4426950408889634f * x);
    return __builtin_amdgcn_rcpf(1.0f + e);
}
__device__ __forceinline__ float tanh_f(float x) {
    float e = __builtin_amdgcn_exp2f(-2.8853900817779268f * x);
    return fmaf(2.0f, __builtin_amdgcn_rcpf(1.0f + e), -1.0f);
}
__device__ __forceinline__ unsigned short f2bf(float f) {  // RNE f32->bf16
    unsigned u = __builtin_bit_cast(unsigned, f);
    u = u + 0x7FFFu + ((u >> 16) & 1u);
    return (unsigned short)(u >> 16);
}

__global__ __attribute__((amdgpu_flat_work_group_size(256, 256),
                          amdgpu_waves_per_eu(2, 2)))
void lstm_mfma_kernel(
    const float* __restrict__ x,      // [B, 1, T]
    const float* __restrict__ W_ih,   // [256, 1]
    const float* __restrict__ W_hh,   // [256, 64]
    const float* __restrict__ b_ih,   // [256]
    const float* __restrict__ b_hh,   // [256]
    const float* __restrict__ fc1_w,  // [64, 64]
    const float* __restrict__ fc1_b,  // [64]
    const float* __restrict__ fc2_w,  // [10, 64]
    const float* __restrict__ fc2_b,  // [10]
    float* __restrict__ out)          // [B, 10]
{
    const int tid  = threadIdx.x;
    const int lane = tid & 63;
    const int w    = tid >> 6;        // wave id = gate (compute) = row (update)
    const int quad = lane >> 4;
    const int col  = lane & 15;
    const int row0 = blockIdx.x * ROWS;

    // ---- LDS union: 32KB staging (dead after B-frag load) overlaps runtime ----
    __shared__ __align__(16) char smem[32768];
    short* whi = (short*)smem;                 // staging [0,32768)
    // runtime (valid only after the staging->register handoff sync):
    short (*abuf)[1088]        = (short(*)[1088])smem;              // 4352 B
    float (*gbuf)[4][HID]      = (float(*)[4][HID])(smem + 4352);   // 4096 B
    float (*xlds)[XCH + 4]     = (float(*)[XCH + 4])(smem + 8448);  // 2112 B
    float (*hf)[HID + 1]       = (float(*)[HID + 1])(smem + 10560); // 1040 B
    float (*r1buf)[HID + 1]    = (float(*)[HID + 1])(smem + 11600); // 1040 B

    // ---- stage: W_hh f32 -> bf16 fragments (R5-verified layout) ----
    for (int idx = tid; idx < 256 * 64; idx += 256) {
        int r_ = idx >> 6;            // gate-major row 0..255
        int k  = idx & 63;
        float f = W_hh[r_ * 64 + k];
        int g = r_ >> 6, u = r_ & 63;
        int u4 = u >> 4, n = u & 15;
        int kt = k >> 5, kq = (k & 31) >> 3, j = k & 7;
        int off = (((u4 * 4 + g) * 2 + kt) * 64 + (kq * 16 + n)) * 8 + j;
        whi[off] = (short)f2bf(f);
    }
    __syncthreads();

    // ---- B fragments -> registers (wave w = gate g, all 4 unit tiles) ----
    const int g = w;
    bf16x8 Bq[4][2];
    f32x4 biasC[4];
    #pragma unroll
    for (int tt = 0; tt < 4; ++tt) {
        int t_ = tt * 4 + g;
        #pragma unroll
        for (int kt = 0; kt < 2; ++kt) {
            int off = ((t_ * 2 + kt) * 64 + lane) * 8;
            Bq[tt][kt] = *(const bf16x8*)&whi[off];
            asm volatile("" : "+v"(Bq[tt][kt]));
        }
        int u = tt * 16 + col;
        float bs = b_ih[g * HID + u] + b_hh[g * HID + u];
        #pragma unroll
        for (int r = 0; r < 4; ++r) biasC[tt][r] = bs;
    }
    __syncthreads();   // all waves done READING staging; smem may be reused now

    // zero BOTH A buffers (rows 4..15 never written -> stay zero = h0)
    for (int idx = tid; idx < 2 * 1088; idx += 256) ((short*)abuf)[idx] = 0;

    // ---- update-phase constants: cell (row m = w, unit = lane) ----
    float wih_u[4];
    #pragma unroll
    for (int gg = 0; gg < 4; ++gg) wih_u[gg] = W_ih[gg * HID + lane];
    float cc = 0.f, hl = 0.f;

    // invariant LDS coords
    const int ard0 = lane * 8 + (lane >> 4) * 8;   // A-read (kt=1 at +544)
    const int s_w  = (lane >> 5) * 4 + ((lane >> 3) & 3);
    const int awr  = (s_w * 16 + w) * 8 + s_w * 8 + (lane & 7);  // h-write (m=w)

    const float* xbase = x + (size_t)row0 * T_STEPS;
    __syncthreads();   // abuf zeroed

    auto step = [&](auto cur_c, int tl) __attribute__((always_inline)) {
        constexpr int CUR = decltype(cur_c)::value;
        constexpr int NXT = CUR ^ 1;

        // ---- compute phase: gate w over all 64 units, single-pass (8 MFMA) ----
        bf16x8 Ahi0 = *(const bf16x8*)&abuf[CUR][ard0];
        bf16x8 Ahi1 = *(const bf16x8*)&abuf[CUR][ard0 + 544];

        f32x4 acc[4];
        #pragma unroll
        for (int tt = 0; tt < 4; ++tt) {
            acc[tt] = __builtin_amdgcn_mfma_f32_16x16x32_bf16(Ahi0, Bq[tt][0], biasC[tt], 0, 0, 0);
        }
        #pragma unroll
        for (int tt = 0; tt < 4; ++tt) {
            acc[tt] = __builtin_amdgcn_mfma_f32_16x16x32_bf16(Ahi1, Bq[tt][1], acc[tt], 0, 0, 0);
        }

        // valid rows m = quad*4+r < 4 -> quad==0, r in 0..3
        // gbuf[m][g][u]: 16 consecutive dwords per tile write -> conflict-free.
        if (quad == 0) {
            #pragma unroll
            for (int tt = 0; tt < 4; ++tt) {
                int u = tt * 16 + col;
                #pragma unroll
                for (int r = 0; r < 4; ++r) gbuf[r][g][u] = acc[tt][r];
            }
        }
        __syncthreads();   // gates visible

        // ---- update phase: ALL 4 waves, 1 cell/thread (row w, unit lane) ----
        {
            float g0 = gbuf[w][0][lane];   // stride-1 b32 reads (2-way = free)
            float g1 = gbuf[w][1][lane];
            float g2 = gbuf[w][2][lane];
            float g3 = gbuf[w][3][lane];
            float xv = xlds[w][tl];        // wave-uniform broadcast

            float a0 = fmaf(xv, wih_u[0], g0);
            float a1 = fmaf(xv, wih_u[1], g1);
            float a2 = fmaf(xv, wih_u[2], g2);
            float a3 = fmaf(xv, wih_u[3], g3);
            float ig = sigm(a0);
            float fg = sigm(a1);
            float gg = tanh_f(a2);
            float og = sigm(a3);
            cc = fmaf(fg, cc, ig * gg);
            float h = og * tanh_f(cc);
            hl = h;

            abuf[NXT][awr] = (short)f2bf(h);
        }
        __syncthreads();   // new h-frags visible
    };

    #pragma unroll 1
    for (int tc = 0; tc < T_STEPS; tc += 2) {
        const int tl = tc & (XCH - 1);
        if (tl == 0) {
            // refill x chunk (prev barrier => old chunk fully consumed)
            if (tid < 16 * ROWS) {
                int xr = tid >> 4, tb = (tid & 15) * 8;
                const float* src = xbase + (size_t)xr * T_STEPS + tc + tb;
                float4 v0 = *(const float4*)(src);
                float4 v1 = *(const float4*)(src + 4);
                *(float4*)&xlds[xr][tb]     = v0;
                *(float4*)&xlds[xr][tb + 4] = v1;
            }
            __syncthreads();
        }
        step(std::integral_constant<int, 0>{}, tl);      // reads abuf[0], writes abuf[1]
        step(std::integral_constant<int, 1>{}, tl + 1);  // reads abuf[1], writes abuf[0]
    }

    // ---- epilogue: fc1 (relu) + fc2 ----
    hf[w][lane] = hl;   // row w, unit lane
    __syncthreads();

    {
        // thread -> (row = w, unit = lane)
        float s = fc1_b[lane];
        const float4* wrow = (const float4*)(fc1_w + lane * HID);
        #pragma unroll
        for (int j4 = 0; j4 < HID / 4; ++j4) {
            float4 wv = wrow[j4];
            s = fmaf(hf[w][j4 * 4 + 0], wv.x, s);
            s = fmaf(hf[w][j4 * 4 + 1], wv.y, s);
            s = fmaf(hf[w][j4 * 4 + 2], wv.z, s);
            s = fmaf(hf[w][j4 * 4 + 3], wv.w, s);
        }
        r1buf[w][lane] = fmaxf(s, 0.0f);
    }
    __syncthreads();

    if (tid < ROWS * NCLS) {
        int m = tid / NCLS, cls = tid % NCLS;
        float s = fc2_b[cls];
        const float* w2 = fc2_w + cls * HID;
        #pragma unroll
        for (int j = 0; j < HID; ++j) s = fmaf(r1buf[m][j], w2[j], s);
        out[(size_t)(row0 + m) * NCLS + cls] = s;
    }
}

extern "C" void kernel_launch(void* const* d_in, const int* in_sizes, int n_in,
                              void* d_out, int out_size, void* d_ws, size_t ws_size,
                              hipStream_t stream) {
    const float* x     = (const float*)d_in[0];
    const float* W_ih  = (const float*)d_in[1];
    const float* W_hh  = (const float*)d_in[2];
    const float* b_ih  = (const float*)d_in[3];
    const float* b_hh  = (const float*)d_in[4];
    const float* fc1_w = (const float*)d_in[5];
    const float* fc1_b = (const float*)d_in[6];
    const float* fc2_w = (const float*)d_in[7];
    const float* fc2_b = (const float*)d_in[8];
    float* out = (float*)d_out;

    dim3 grid(256);   // 1024 rows / 4 rows per block -> 1 block per CU
    dim3 block(256);  // 4 waves
    lstm_mfma_kernel<<<grid, block, 0, stream>>>(x, W_ih, W_hh, b_ih, b_hh,
                                                 fc1_w, fc1_b, fc2_w, fc2_b, out);
}